// Round 1
// baseline (72.190 us; speedup 1.0000x reference)
//
#include <hip/hip_runtime.h>

// DynamicKoopmanOperator:
//   h    = tanh(x @ W1 + b1)                      [B,K]
//   eigs = (h @ W2 + b2).reshape(B, K/2, 2)       mu = eigs[...,0], om = eigs[...,1]
//   c    = exp(mu*dt) * e^{i*om*dt}   (per pair)
//   preds[b,t,:] = c^{t+1} applied pairwise to x[b,:]   (rollout is a fixed
//   complex multiply per step -> closed form at any t; we chunk T for parallelism)

#define DT_CONST 0.01f

constexpr int KDIM  = 256;   // feature dim
constexpr int NE    = 128;   // num eigen-pairs = K/2
constexpr int ROWS  = 8;     // batch rows per MLP block
constexpr int CHUNK = 32;    // timesteps per rollout block

// ---------------- Kernel A: parameterization MLP -> (mu*dt, om*dt) ----------
__global__ __launch_bounds__(256) void koopman_mlp(
    const float* __restrict__ x,  const float* __restrict__ W1,
    const float* __restrict__ b1, const float* __restrict__ W2,
    const float* __restrict__ b2, float2* __restrict__ coef)
{
    __shared__ float xs[ROWS][KDIM];   // x rows, later reused for eigs
    __shared__ float hs[ROWS][KDIM];   // tanh hidden

    const int j  = threadIdx.x;        // output column 0..255
    const int b0 = blockIdx.x * ROWS;

    // stage 8 x-rows into LDS (coalesced)
    for (int i = j; i < ROWS * KDIM; i += 256) {
        int r = i >> 8, k = i & (KDIM - 1);
        xs[r][k] = x[(size_t)(b0 + r) * KDIM + k];
    }
    __syncthreads();

    // GEMM 1: h[r][j] = tanh(sum_k xs[r][k] * W1[k][j] + b1[j])
    float acc[ROWS];
    {
        float bj = b1[j];
#pragma unroll
        for (int r = 0; r < ROWS; ++r) acc[r] = bj;
        for (int k = 0; k < KDIM; ++k) {
            float wk = W1[(size_t)k * KDIM + j];   // coalesced across threads
#pragma unroll
            for (int r = 0; r < ROWS; ++r) acc[r] = fmaf(xs[r][k], wk, acc[r]);
        }
#pragma unroll
        for (int r = 0; r < ROWS; ++r) hs[r][j] = tanhf(acc[r]);
    }
    __syncthreads();

    // GEMM 2: eigs[r][j] = sum_k hs[r][k] * W2[k][j] + b2[j]  (write into xs)
    {
        float bj = b2[j];
#pragma unroll
        for (int r = 0; r < ROWS; ++r) acc[r] = bj;
        for (int k = 0; k < KDIM; ++k) {
            float wk = W2[(size_t)k * KDIM + j];
#pragma unroll
            for (int r = 0; r < ROWS; ++r) acc[r] = fmaf(hs[r][k], wk, acc[r]);
        }
#pragma unroll
        for (int r = 0; r < ROWS; ++r) xs[r][j] = acc[r];  // xs no longer read
    }
    __syncthreads();

    // pair up (mu, om), pre-scale by dt, emit float2 per (batch, pair)
    if (j < NE) {
#pragma unroll
        for (int r = 0; r < ROWS; ++r) {
            float mu = xs[r][2 * j];
            float om = xs[r][2 * j + 1];
            coef[(size_t)(b0 + r) * NE + j] = make_float2(mu * DT_CONST, om * DT_CONST);
        }
    }
}

// ---------------- Kernel B: rollout, chunked over T ------------------------
__global__ __launch_bounds__(128) void koopman_rollout(
    const float* __restrict__ x, const float2* __restrict__ coef,
    float* __restrict__ out, int T)
{
    const int e  = threadIdx.x;            // pair index 0..127
    const int b  = blockIdx.x;             // batch row
    const int t0 = blockIdx.y * CHUNK;     // first output timestep of this chunk

    float2 mo = coef[(size_t)b * NE + e];  // (mu*dt, om*dt)
    float x0 = x[(size_t)b * KDIM + 2 * e];
    float x1 = x[(size_t)b * KDIM + 2 * e + 1];

    // seed: z = M^{t0} x  (closed form — removes the sequential dependency)
    float rp = expf(mo.x * (float)t0);
    float sp, cp;
    sincosf(mo.y * (float)t0, &sp, &cp);
    float z0 = rp * (cp * x0 - sp * x1);
    float z1 = rp * (sp * x0 + cp * x1);

    // per-step multiplier a + i*bb
    float r1 = expf(mo.x);
    float s1, c1;
    sincosf(mo.y, &s1, &c1);
    float a = r1 * c1, bb = r1 * s1;

    float2* orow = reinterpret_cast<float2*>(out + (size_t)b * T * KDIM) + e;
    const int tend = (t0 + CHUNK < T) ? (t0 + CHUNK) : T;
#pragma unroll 4
    for (int t = t0; t < tend; ++t) {
        float nz0 = a * z0 - bb * z1;
        float nz1 = bb * z0 + a * z1;
        orow[(size_t)t * NE] = make_float2(nz0, nz1);  // 512B contiguous per wave
        z0 = nz0; z1 = nz1;
    }
}

// ---------------- launcher ---------------------------------------------------
extern "C" void kernel_launch(void* const* d_in, const int* in_sizes, int n_in,
                              void* d_out, int out_size, void* d_ws, size_t ws_size,
                              hipStream_t stream) {
    const float* x  = (const float*)d_in[0];
    const float* W1 = (const float*)d_in[1];
    const float* b1 = (const float*)d_in[2];
    const float* W2 = (const float*)d_in[3];
    const float* b2 = (const float*)d_in[4];

    const int Kd = in_sizes[2];                 // 256
    const int Bb = in_sizes[0] / Kd;            // 1024
    const int T  = out_size / (Bb * Kd);        // 256

    float2* coef = (float2*)d_ws;               // B * NE float2 = 1 MiB
    float*  out  = (float*)d_out;

    koopman_mlp<<<Bb / ROWS, 256, 0, stream>>>(x, W1, b1, W2, b2, coef);

    dim3 grid(Bb, (T + CHUNK - 1) / CHUNK);
    koopman_rollout<<<grid, NE, 0, stream>>>(x, coef, out, T);
}